// Round 5
// baseline (458.646 us; speedup 1.0000x reference)
//
#include <hip/hip_runtime.h>

#define N_NODES 8192
#define FDIM 128
#define NEG_SLOPE 0.2f
#define SEG 512   // per-wave neighbor capacity (mean ~102, 5 sigma headroom)

// float -> bf16 bits, round-to-nearest-even (values are all normal finite)
__device__ __forceinline__ unsigned int f2bf(float f) {
  unsigned int u = __float_as_uint(f);
  return (u + 0x7FFFu + ((u >> 16) & 1u)) >> 16;
}

// ---------------- Kernel 0: WtG = W^T (one-time, 64 KB) -------------------
__global__ __launch_bounds__(256) void transpose_w_kernel(
    const float* __restrict__ W, float* __restrict__ WtG) {
  int idx = blockIdx.x * 256 + threadIdx.x;       // idx = k*128+o of WtG
  WtG[idx] = W[(idx & 127) * FDIM + (idx >> 7)];  // strided read, coalesced write
}

// ---------------- Kernel A: Whb(bf16) = h @ W.T, colsum S, s1/s2 scores ----
__global__ __launch_bounds__(256) void wh_fused_kernel(
    const float* __restrict__ h, const float* __restrict__ WtG,
    const float* __restrict__ a,
    unsigned int* __restrict__ Whb,   // packed bf16x2: N rows x 64 uints
    float* __restrict__ s1, float* __restrict__ s2,
    float* __restrict__ S) {
  __shared__ float Wt[FDIM * 132];   // Wt[k*132+o] (67.6 KB)
  __shared__ float rows[32 * 132];   // rows[r*132+k]; reused as colsum scratch
  const int t = threadIdx.x;
  const int base = blockIdx.x * 32;
  for (int it = 0; it < 16; ++it) {
    int idx = t + 256 * it;          // float4 index into WtG
    int k = idx >> 5, c = (idx & 31) * 4;
    *(float4*)&Wt[k * 132 + c] = *(const float4*)&WtG[k * FDIM + c];
  }
  for (int it = 0; it < 4; ++it) {
    int idx = t + 256 * it;
    int r = idx >> 5, c = (idx & 31) * 4;
    *(float4*)&rows[r * 132 + c] =
        *(const float4*)&h[(size_t)(base + r) * FDIM + c];
  }
  __syncthreads();
  const int c4 = (t & 31) * 4;
  const int g = t >> 5;              // 8 groups x 4 rows
  float acc[4][4];
#pragma unroll
  for (int rr = 0; rr < 4; ++rr)
#pragma unroll
    for (int cc = 0; cc < 4; ++cc) acc[rr][cc] = 0.f;
  for (int k = 0; k < FDIM; ++k) {
    float4 wv = *(const float4*)&Wt[k * 132 + c4];   // b128, conflict-free
    float rv[4];
#pragma unroll
    for (int rr = 0; rr < 4; ++rr) rv[rr] = rows[(4 * g + rr) * 132 + k];
#pragma unroll
    for (int rr = 0; rr < 4; ++rr) {
      acc[rr][0] += rv[rr] * wv.x;
      acc[rr][1] += rv[rr] * wv.y;
      acc[rr][2] += rv[rr] * wv.z;
      acc[rr][3] += rv[rr] * wv.w;
    }
  }
#pragma unroll
  for (int rr = 0; rr < 4; ++rr) {
    int r = base + 4 * g + rr;
    unsigned int p0 = f2bf(acc[rr][0]) | (f2bf(acc[rr][1]) << 16);
    unsigned int p1 = f2bf(acc[rr][2]) | (f2bf(acc[rr][3]) << 16);
    *(uint2*)&Whb[(size_t)r * 64 + (c4 >> 1)] = make_uint2(p0, p1);
  }
  {
    float4 a1v = *(const float4*)&a[c4];
    float4 a2v = *(const float4*)&a[FDIM + c4];
#pragma unroll
    for (int rr = 0; rr < 4; ++rr) {
      float d1 = acc[rr][0] * a1v.x + acc[rr][1] * a1v.y +
                 acc[rr][2] * a1v.z + acc[rr][3] * a1v.w;
      float d2 = acc[rr][0] * a2v.x + acc[rr][1] * a2v.y +
                 acc[rr][2] * a2v.z + acc[rr][3] * a2v.w;
#pragma unroll
      for (int off = 16; off; off >>= 1) {
        d1 += __shfl_down(d1, off);
        d2 += __shfl_down(d2, off);
      }
      if ((t & 31) == 0) {
        s1[base + 4 * g + rr] = d1;
        s2[base + 4 * g + rr] = d2;
      }
    }
  }
  __syncthreads();
  float4 cs = make_float4(acc[0][0] + acc[1][0] + acc[2][0] + acc[3][0],
                          acc[0][1] + acc[1][1] + acc[2][1] + acc[3][1],
                          acc[0][2] + acc[1][2] + acc[2][2] + acc[3][2],
                          acc[0][3] + acc[1][3] + acc[2][3] + acc[3][3]);
  *(float4*)&rows[g * FDIM + c4] = cs;
  __syncthreads();
  if (t < FDIM) {
    float s = 0.f;
#pragma unroll
    for (int gg = 0; gg < 8; ++gg) s += rows[gg * FDIM + t];
    atomicAdd(&S[t], s);
  }
}

// non-temporal float4 load: adj is streamed exactly once — bypass caches.
__device__ __forceinline__ float4 ntload4(const float4* p) {
  typedef float f4v __attribute__((ext_vector_type(4)));
  f4v v = __builtin_nontemporal_load((const f4v*)p);
  return make_float4(v[0], v[1], v[2], v[3]);
}

// exact wave64 prefix-popcount of ballot mask below this lane (2 VALU ops)
__device__ __forceinline__ int mbcnt64(unsigned long long b) {
  return (int)__builtin_amdgcn_mbcnt_hi(
      (unsigned)(b >> 32), __builtin_amdgcn_mbcnt_lo((unsigned)b, 0u));
}

// ---------------- Kernel B1: streaming scan/compact ----------------
// one block (4 waves) per row. PURE streaming: no LDS, no barriers — each
// wave independently compacts its quarter-row into a global per-wave segment
// and writes its count + running max. Single-resource kernel: should run at
// HBM streaming BW (268 MB / ~5.5 TB/s ~ 50 us) instead of time-slicing HBM
// with the gather (the phase-alignment stall behind rounds 2-4's plateau).
__global__ __launch_bounds__(256, 4) void scan_kernel(
    const float* __restrict__ adj, const float* __restrict__ s1,
    const float* __restrict__ s2, float2* __restrict__ pairs,
    int* __restrict__ cnt4, float* __restrict__ wmax) {
  const int i = blockIdx.x;
  const int t = threadIdx.x;
  const int lane = t & 63, wave = t >> 6;
  const float s1i = s1[i];
  const float4* __restrict__ arow = (const float4*)(adj + (size_t)i * N_NODES);
  const float4* __restrict__ srow = (const float4*)s2;
  float2* __restrict__ mypairs = pairs + (size_t)i * (4 * SEG) + wave * SEG;

  float4 av[8], sv[8];
#pragma unroll
  for (int it = 0; it < 8; ++it) av[it] = ntload4(&arow[it * 256 + t]);
#pragma unroll
  for (int it = 0; it < 8; ++it) sv[it] = srow[it * 256 + t];
  int cbase = 0;
  float lmax = -1e30f;
#pragma unroll
  for (int it = 0; it < 8; ++it) {
    const int j4 = it * 256 + t;
    float vv[4] = {av[it].x, av[it].y, av[it].z, av[it].w};
    float ss[4] = {sv[it].x, sv[it].y, sv[it].z, sv[it].w};
#pragma unroll
    for (int c = 0; c < 4; ++c) {
      bool pred = (vv[c] != 0.f);
      float e = s1i + ss[c];
      e = e > 0.f ? e : NEG_SLOPE * e;
      unsigned long long b = __ballot(pred);
      if (pred) {
        int pos = cbase + mbcnt64(b);
        if (pos < SEG) {
          float2 pr;
          pr.x = e;
          ((int*)&pr)[1] = j4 * 4 + c;
          mypairs[pos] = pr;
        }
      }
      lmax = fmaxf(lmax, pred ? e : -1e30f);
      cbase += (int)__popcll(b);
    }
  }
  const int mycnt = cbase < SEG ? cbase : SEG;
  for (int off = 32; off; off >>= 1) lmax = fmaxf(lmax, __shfl_down(lmax, off));
  if (lane == 0) {
    cnt4[4 * i + wave] = mycnt;
    wmax[4 * i + wave] = lmax;
  }
}

// ---------------- Kernel B2: softmax weights + sparse gather ----------------
// one block (4 waves) per row. PURE L2-gather + VALU kernel (no HBM stream).
// quarter-wave (16 lanes) per pair: uint4 = 16 B/lane covers the 256 B bf16
// row; 2x fewer load instructions and half the exp redundancy vs half-wave.
// LDS only 2.1 KB -> high occupancy.
__global__ __launch_bounds__(256, 4) void gather_kernel(
    const unsigned int* __restrict__ Whb, const float2* __restrict__ pairs,
    const int* __restrict__ cnt4, const float* __restrict__ wmax,
    const float* __restrict__ S, float* __restrict__ out) {
  const int i = blockIdx.x;
  const int t = threadIdx.x;
  const int lane = t & 63, wave = t >> 6;
  __shared__ float fpart[4][FDIM];
  __shared__ float red2[4];

  const int4 cc = *(const int4*)&cnt4[4 * i];
  const float4 wm = *(const float4*)&wmax[4 * i];
  const int cnt = cc.x + cc.y + cc.z + cc.w;
  const int mycnt = wave == 0 ? cc.x : wave == 1 ? cc.y : wave == 2 ? cc.z : cc.w;
  float m = fmaxf(fmaxf(wm.x, wm.y), fmaxf(wm.z, wm.w));
  if (cnt < N_NODES) m = fmaxf(m, 0.f);  // adj==0 entries contribute z=0
  const float em = __expf(-m);

  const float2* __restrict__ mypairs = pairs + (size_t)i * (4 * SEG) + wave * SEG;
  const int q = lane >> 4, lq = lane & 15;
  const uint4* __restrict__ Whb4 = (const uint4*)Whb;  // 16 uint4 per row
  float acc[8];
#pragma unroll
  for (int e = 0; e < 8; ++e) acc[e] = 0.f;
  float lsum = 0.f;
  const int nit = (mycnt + 3) >> 2;
  for (int it = 0; it < nit; ++it) {
    int p = 4 * it + q;
    bool ok = p < mycnt;
    float2 pr = mypairs[ok ? p : 0];
    int j = ((const int*)&pr)[1] & (N_NODES - 1);  // mask: poison-safe
    uint4 d = Whb4[((size_t)j << 4) + lq];
    float pv = __expf(pr.x - m);
    float w = ok ? pv - em : 0.f;
    lsum += ok ? pv : 0.f;
    acc[0] += w * __uint_as_float(d.x << 16);
    acc[1] += w * __uint_as_float(d.x & 0xffff0000u);
    acc[2] += w * __uint_as_float(d.y << 16);
    acc[3] += w * __uint_as_float(d.y & 0xffff0000u);
    acc[4] += w * __uint_as_float(d.z << 16);
    acc[5] += w * __uint_as_float(d.z & 0xffff0000u);
    acc[6] += w * __uint_as_float(d.w << 16);
    acc[7] += w * __uint_as_float(d.w & 0xffff0000u);
  }
  // lsum: each pair was counted by its 16-lane quarter
  for (int off = 32; off; off >>= 1) lsum += __shfl_down(lsum, off);
  if (lane == 0) red2[wave] = lsum * (1.f / 16.f);
  // combine the 4 quarter groups (same features, disjoint pair subsets)
#pragma unroll
  for (int e = 0; e < 8; ++e) {
    acc[e] += __shfl_down(acc[e], 32);
    acc[e] += __shfl_down(acc[e], 16);
  }
  if (lane < 16) {
    *(float4*)&fpart[wave][lq * 8] = make_float4(acc[0], acc[1], acc[2], acc[3]);
    *(float4*)&fpart[wave][lq * 8 + 4] = make_float4(acc[4], acc[5], acc[6], acc[7]);
  }
  __syncthreads();
  if (t < FDIM) {
    float l = red2[0] + red2[1] + red2[2] + red2[3]
              + (float)(N_NODES - cnt) * em;
    float o = (fpart[0][t] + fpart[1][t] + fpart[2][t] + fpart[3][t]
               + em * S[t]) / l;
    out[(size_t)i * FDIM + t] = o;
  }
}

extern "C" void kernel_launch(void* const* d_in, const int* in_sizes, int n_in,
                              void* d_out, int out_size, void* d_ws, size_t ws_size,
                              hipStream_t stream) {
  const float* h   = (const float*)d_in[0];
  const float* adj = (const float*)d_in[1];
  const float* W   = (const float*)d_in[2];
  const float* a   = (const float*)d_in[3];
  float* out = (float*)d_out;
  // workspace (4B units):
  // Whb 524288 | s1 8192 | s2 8192 | S 128 | WtG 16384 | cnt4 32768 |
  // wmax 32768 | pairs 8192*2048 float2  (total ~137 MB)
  unsigned int* Whb = (unsigned int*)d_ws;
  float* s1   = (float*)(Whb + (size_t)N_NODES * 64);
  float* s2   = s1 + N_NODES;
  float* S    = s2 + N_NODES;
  float* WtG  = S + FDIM;
  int*   cnt4 = (int*)(WtG + FDIM * FDIM);
  float* wmax = (float*)(cnt4 + 4 * N_NODES);
  float2* pairs = (float2*)(wmax + 4 * N_NODES);

  hipMemsetAsync(S, 0, FDIM * sizeof(float), stream);
  hipLaunchKernelGGL(transpose_w_kernel, dim3(FDIM * FDIM / 256), dim3(256), 0,
                     stream, W, WtG);
  hipLaunchKernelGGL(wh_fused_kernel, dim3(N_NODES / 32), dim3(256), 0, stream,
                     h, WtG, a, Whb, s1, s2, S);
  hipLaunchKernelGGL(scan_kernel, dim3(N_NODES), dim3(256), 0, stream,
                     adj, s1, s2, pairs, cnt4, wmax);
  hipLaunchKernelGGL(gather_kernel, dim3(N_NODES), dim3(256), 0, stream,
                     Whb, pairs, cnt4, wmax, S, out);
}

// Round 6
// 417.161 us; speedup vs baseline: 1.0994x; 1.0994x over previous
//
#include <hip/hip_runtime.h>

#define N_NODES 8192
#define FDIM 128
#define NEG_SLOPE 0.2f
#define SEG 512   // per-wave neighbor capacity (mean ~102, 5 sigma headroom)
#define ROWS 4    // rows per block in gat_pipe (cross-row pipelining depth)

// float -> bf16 bits, round-to-nearest-even (values are all normal finite)
__device__ __forceinline__ unsigned int f2bf(float f) {
  unsigned int u = __float_as_uint(f);
  return (u + 0x7FFFu + ((u >> 16) & 1u)) >> 16;
}

// ---------------- Kernel 0: WtG = W^T (one-time, 64 KB) -------------------
__global__ __launch_bounds__(256) void transpose_w_kernel(
    const float* __restrict__ W, float* __restrict__ WtG) {
  int idx = blockIdx.x * 256 + threadIdx.x;       // idx = k*128+o of WtG
  WtG[idx] = W[(idx & 127) * FDIM + (idx >> 7)];  // strided read, coalesced write
}

// ---------------- Kernel A: Whb(bf16) = h @ W.T, colsum S, s1/s2 scores ----
__global__ __launch_bounds__(256) void wh_fused_kernel(
    const float* __restrict__ h, const float* __restrict__ WtG,
    const float* __restrict__ a,
    unsigned int* __restrict__ Whb,   // packed bf16x2: N rows x 64 uints
    float* __restrict__ s1, float* __restrict__ s2,
    float* __restrict__ S) {
  __shared__ float Wt[FDIM * 132];   // Wt[k*132+o] (67.6 KB)
  __shared__ float rows[32 * 132];   // rows[r*132+k]; reused as colsum scratch
  const int t = threadIdx.x;
  const int base = blockIdx.x * 32;
  for (int it = 0; it < 16; ++it) {
    int idx = t + 256 * it;          // float4 index into WtG
    int k = idx >> 5, c = (idx & 31) * 4;
    *(float4*)&Wt[k * 132 + c] = *(const float4*)&WtG[k * FDIM + c];
  }
  for (int it = 0; it < 4; ++it) {
    int idx = t + 256 * it;
    int r = idx >> 5, c = (idx & 31) * 4;
    *(float4*)&rows[r * 132 + c] =
        *(const float4*)&h[(size_t)(base + r) * FDIM + c];
  }
  __syncthreads();
  const int c4 = (t & 31) * 4;
  const int g = t >> 5;              // 8 groups x 4 rows
  float acc[4][4];
#pragma unroll
  for (int rr = 0; rr < 4; ++rr)
#pragma unroll
    for (int cc = 0; cc < 4; ++cc) acc[rr][cc] = 0.f;
  for (int k = 0; k < FDIM; ++k) {
    float4 wv = *(const float4*)&Wt[k * 132 + c4];   // b128, conflict-free
    float rv[4];
#pragma unroll
    for (int rr = 0; rr < 4; ++rr) rv[rr] = rows[(4 * g + rr) * 132 + k];
#pragma unroll
    for (int rr = 0; rr < 4; ++rr) {
      acc[rr][0] += rv[rr] * wv.x;
      acc[rr][1] += rv[rr] * wv.y;
      acc[rr][2] += rv[rr] * wv.z;
      acc[rr][3] += rv[rr] * wv.w;
    }
  }
#pragma unroll
  for (int rr = 0; rr < 4; ++rr) {
    int r = base + 4 * g + rr;
    unsigned int p0 = f2bf(acc[rr][0]) | (f2bf(acc[rr][1]) << 16);
    unsigned int p1 = f2bf(acc[rr][2]) | (f2bf(acc[rr][3]) << 16);
    *(uint2*)&Whb[(size_t)r * 64 + (c4 >> 1)] = make_uint2(p0, p1);
  }
  {
    float4 a1v = *(const float4*)&a[c4];
    float4 a2v = *(const float4*)&a[FDIM + c4];
#pragma unroll
    for (int rr = 0; rr < 4; ++rr) {
      float d1 = acc[rr][0] * a1v.x + acc[rr][1] * a1v.y +
                 acc[rr][2] * a1v.z + acc[rr][3] * a1v.w;
      float d2 = acc[rr][0] * a2v.x + acc[rr][1] * a2v.y +
                 acc[rr][2] * a2v.z + acc[rr][3] * a2v.w;
#pragma unroll
      for (int off = 16; off; off >>= 1) {
        d1 += __shfl_down(d1, off);
        d2 += __shfl_down(d2, off);
      }
      if ((t & 31) == 0) {
        s1[base + 4 * g + rr] = d1;
        s2[base + 4 * g + rr] = d2;
      }
    }
  }
  __syncthreads();
  float4 cs = make_float4(acc[0][0] + acc[1][0] + acc[2][0] + acc[3][0],
                          acc[0][1] + acc[1][1] + acc[2][1] + acc[3][1],
                          acc[0][2] + acc[1][2] + acc[2][2] + acc[3][2],
                          acc[0][3] + acc[1][3] + acc[2][3] + acc[3][3]);
  *(float4*)&rows[g * FDIM + c4] = cs;
  __syncthreads();
  if (t < FDIM) {
    float s = 0.f;
#pragma unroll
    for (int gg = 0; gg < 8; ++gg) s += rows[gg * FDIM + t];
    atomicAdd(&S[t], s);
  }
}

// non-temporal float4 load: adj is streamed exactly once — bypass caches.
__device__ __forceinline__ float4 ntload4(const float4* p) {
  typedef float f4v __attribute__((ext_vector_type(4)));
  f4v v = __builtin_nontemporal_load((const f4v*)p);
  return make_float4(v[0], v[1], v[2], v[3]);
}

// exact wave64 prefix-popcount of ballot mask below this lane (2 VALU ops)
__device__ __forceinline__ int mbcnt64(unsigned long long b) {
  return (int)__builtin_amdgcn_mbcnt_hi(
      (unsigned)(b >> 32), __builtin_amdgcn_mbcnt_lo((unsigned)b, 0u));
}

// ---------------- Kernel B: cross-row pipelined softmax + gather ----------
// ROWS consecutive rows per block, a0/a1 adj register double-buffer.
// KEY: adj loads for row r+1 are issued right after row r's ballot consumes
// its loads and BEFORE row r's gather — so the HBM stream stays loaded during
// the gather/VALU phase. (All previous variants kept scan and gather strictly
// sequential per block: adj loads were in flight only ~20% of block lifetime,
// capping the stream at ~2 TB/s. Duty-cycle fix, not phase-order fix.)
__global__ __launch_bounds__(256, 4) void gat_pipe_kernel(
    const float* __restrict__ adj, const unsigned int* __restrict__ Whb,
    const float* __restrict__ s1, const float* __restrict__ s2,
    const float* __restrict__ S, float* __restrict__ out) {
  const int t = threadIdx.x;
  const int lane = t & 63, wave = t >> 6;
  __shared__ float2 pairs[4 * SEG];  // per-wave segments; .x=e .y=j bits
  __shared__ int counts[4];
  __shared__ float red[4];           // per-wave max
  __shared__ float red2[4];          // per-wave exp-sum
  __shared__ float fpart[4][FDIM];
  float2* __restrict__ mypairs = pairs + wave * SEG;
  const float4* __restrict__ srow = (const float4*)s2;
  const uint4* __restrict__ Whb4 = (const uint4*)Whb;  // 16 uint4 per row
  const int q = lane >> 4, lq = lane & 15;

  const int base = blockIdx.x * ROWS;
  const float4 s1v = *(const float4*)&s1[base];  // ROWS==4, 16B-aligned

  float4 a0[8], a1[8];
#define ISSUE(BUF, ROW)                                                     \
  {                                                                         \
    const float4* __restrict__ ar =                                         \
        (const float4*)(adj + (size_t)(ROW)*N_NODES);                       \
    _Pragma("unroll") for (int it = 0; it < 8; ++it)                        \
        BUF[it] = ntload4(&ar[it * 256 + t]);                               \
  }

#define PROC(AV, RR, DO_NEXT, NEXTBUF)                                      \
  {                                                                         \
    const int i = base + (RR);                                              \
    const float s1i = ((const float*)&s1v)[RR];                             \
    int cbase = 0;                                                          \
    float lmax = -1e30f;                                                    \
    _Pragma("unroll") for (int it = 0; it < 8; ++it) {                      \
      const int j4 = it * 256 + t;                                          \
      float4 svv = srow[it * 256 + t]; /* L1/L2-hot, reloaded per row */    \
      float vv[4] = {AV[it].x, AV[it].y, AV[it].z, AV[it].w};               \
      float ss[4] = {svv.x, svv.y, svv.z, svv.w};                           \
      _Pragma("unroll") for (int c = 0; c < 4; ++c) {                       \
        bool pred = (vv[c] != 0.f);                                         \
        float e = s1i + ss[c];                                              \
        e = e > 0.f ? e : NEG_SLOPE * e;                                    \
        unsigned long long b = __ballot(pred);                              \
        if (pred) {                                                         \
          int pos = cbase + mbcnt64(b);                                     \
          if (pos < SEG) {                                                  \
            float2 pr;                                                      \
            pr.x = e;                                                       \
            ((int*)&pr)[1] = j4 * 4 + c;                                    \
            mypairs[pos] = pr;                                              \
          }                                                                 \
        }                                                                   \
        lmax = fmaxf(lmax, pred ? e : -1e30f);                              \
        cbase += (int)__popcll(b);                                          \
      }                                                                     \
    }                                                                       \
    const int mycnt = cbase < SEG ? cbase : SEG;                            \
    if (lane == 0) counts[wave] = mycnt;                                    \
    for (int off = 32; off; off >>= 1)                                      \
      lmax = fmaxf(lmax, __shfl_down(lmax, off));                           \
    if (lane == 0) red[wave] = lmax;                                        \
    if (DO_NEXT) ISSUE(NEXTBUF, base + (RR) + 1); /* overlap w/ gather */   \
    __syncthreads();                                                        \
    const int cnt = counts[0] + counts[1] + counts[2] + counts[3];          \
    float m = fmaxf(fmaxf(red[0], red[1]), fmaxf(red[2], red[3]));          \
    if (cnt < N_NODES) m = fmaxf(m, 0.f);                                   \
    const float em = __expf(-m);                                            \
    float acc0 = 0.f, acc1 = 0.f, acc2 = 0.f, acc3 = 0.f;                   \
    float acc4 = 0.f, acc5 = 0.f, acc6 = 0.f, acc7 = 0.f;                   \
    float lsum = 0.f;                                                       \
    const int nit = (mycnt + 3) >> 2;                                       \
    for (int itg = 0; itg < nit; ++itg) {                                   \
      int p = 4 * itg + q;                                                  \
      bool ok = p < mycnt;                                                  \
      float2 pr = mypairs[ok ? p : 0];                                      \
      int j = ((const int*)&pr)[1] & (N_NODES - 1);                         \
      uint4 d = Whb4[((size_t)j << 4) + lq];                                \
      float pv = __expf(pr.x - m);                                          \
      float w = ok ? pv - em : 0.f;                                         \
      lsum += ok ? pv : 0.f;                                                \
      acc0 += w * __uint_as_float(d.x << 16);                               \
      acc1 += w * __uint_as_float(d.x & 0xffff0000u);                       \
      acc2 += w * __uint_as_float(d.y << 16);                               \
      acc3 += w * __uint_as_float(d.y & 0xffff0000u);                       \
      acc4 += w * __uint_as_float(d.z << 16);                               \
      acc5 += w * __uint_as_float(d.z & 0xffff0000u);                       \
      acc6 += w * __uint_as_float(d.w << 16);                               \
      acc7 += w * __uint_as_float(d.w & 0xffff0000u);                       \
    }                                                                       \
    for (int off = 32; off; off >>= 1) lsum += __shfl_down(lsum, off);      \
    if (lane == 0) red2[wave] = lsum * (1.f / 16.f);                        \
    acc0 += __shfl_down(acc0, 32); acc0 += __shfl_down(acc0, 16);           \
    acc1 += __shfl_down(acc1, 32); acc1 += __shfl_down(acc1, 16);           \
    acc2 += __shfl_down(acc2, 32); acc2 += __shfl_down(acc2, 16);           \
    acc3 += __shfl_down(acc3, 32); acc3 += __shfl_down(acc3, 16);           \
    acc4 += __shfl_down(acc4, 32); acc4 += __shfl_down(acc4, 16);           \
    acc5 += __shfl_down(acc5, 32); acc5 += __shfl_down(acc5, 16);           \
    acc6 += __shfl_down(acc6, 32); acc6 += __shfl_down(acc6, 16);           \
    acc7 += __shfl_down(acc7, 32); acc7 += __shfl_down(acc7, 16);           \
    if (lane < 16) {                                                        \
      *(float4*)&fpart[wave][lq * 8] = make_float4(acc0, acc1, acc2, acc3); \
      *(float4*)&fpart[wave][lq * 8 + 4] =                                  \
          make_float4(acc4, acc5, acc6, acc7);                              \
    }                                                                       \
    __syncthreads();                                                        \
    if (t < FDIM) {                                                         \
      float l = red2[0] + red2[1] + red2[2] + red2[3] +                     \
                (float)(N_NODES - cnt) * em;                                \
      float o = (fpart[0][t] + fpart[1][t] + fpart[2][t] + fpart[3][t] +    \
                 em * S[t]) / l;                                            \
      out[(size_t)i * FDIM + t] = o;                                        \
    }                                                                       \
  }

  ISSUE(a0, base);
  PROC(a0, 0, 1, a1);
  PROC(a1, 1, 1, a0);
  PROC(a0, 2, 1, a1);
  PROC(a1, 3, 0, a0);
#undef PROC
#undef ISSUE
}

extern "C" void kernel_launch(void* const* d_in, const int* in_sizes, int n_in,
                              void* d_out, int out_size, void* d_ws, size_t ws_size,
                              hipStream_t stream) {
  const float* h   = (const float*)d_in[0];
  const float* adj = (const float*)d_in[1];
  const float* W   = (const float*)d_in[2];
  const float* a   = (const float*)d_in[3];
  float* out = (float*)d_out;
  // workspace (4B units): Whb 524288 | s1 8192 | s2 8192 | S 128 | WtG 16384
  unsigned int* Whb = (unsigned int*)d_ws;
  float* s1  = (float*)(Whb + (size_t)N_NODES * 64);
  float* s2  = s1 + N_NODES;
  float* S   = s2 + N_NODES;
  float* WtG = S + FDIM;

  hipMemsetAsync(S, 0, FDIM * sizeof(float), stream);
  hipLaunchKernelGGL(transpose_w_kernel, dim3(FDIM * FDIM / 256), dim3(256), 0,
                     stream, W, WtG);
  hipLaunchKernelGGL(wh_fused_kernel, dim3(N_NODES / 32), dim3(256), 0, stream,
                     h, WtG, a, Whb, s1, s2, S);
  hipLaunchKernelGGL(gat_pipe_kernel, dim3(N_NODES / ROWS), dim3(256), 0,
                     stream, adj, Whb, s1, s2, S, out);
}

// Round 7
// 404.186 us; speedup vs baseline: 1.1347x; 1.0321x over previous
//
#include <hip/hip_runtime.h>

#define N_NODES 8192
#define FDIM 128
#define NEG_SLOPE 0.2f
#define SEG 512   // per-wave neighbor capacity (mean ~102, huge headroom)

// float -> bf16 bits, round-to-nearest-even (values are all normal finite)
__device__ __forceinline__ unsigned int f2bf(float f) {
  unsigned int u = __float_as_uint(f);
  return (u + 0x7FFFu + ((u >> 16) & 1u)) >> 16;
}

// ---------------- Kernel A: Whb(bf16) = h @ W.T, colsum S, s1/s2 scores ----
// (identical to the measured-best round-2 version)
__global__ __launch_bounds__(256) void wh_fused_kernel(
    const float* __restrict__ h, const float* __restrict__ W,
    const float* __restrict__ a,
    unsigned int* __restrict__ Whb,   // packed bf16x2: N rows x 64 uints
    float* __restrict__ s1, float* __restrict__ s2,
    float* __restrict__ S) {
  __shared__ float Wt[FDIM * 132];   // Wt[k*132+o] = W[o][k]
  __shared__ float rows[32 * 132];   // rows[r*132+k]; reused as colsum scratch
  const int t = threadIdx.x;
  const int base = blockIdx.x * 32;
  for (int it = 0; it < 64; ++it) {
    int idx = t + 256 * it;          // idx = o*128+k
    int o = idx >> 7, k = idx & 127;
    Wt[k * 132 + o] = W[idx];
  }
  for (int it = 0; it < 16; ++it) {
    int idx = t + 256 * it;          // idx = r*128+col
    int r = idx >> 7, col = idx & 127;
    rows[r * 132 + col] = h[(size_t)base * FDIM + idx];
  }
  __syncthreads();
  const int c4 = (t & 31) * 4;
  const int g = t >> 5;
  float acc[4][4];
#pragma unroll
  for (int rr = 0; rr < 4; ++rr)
#pragma unroll
    for (int cc = 0; cc < 4; ++cc) acc[rr][cc] = 0.f;
  for (int k = 0; k < FDIM; ++k) {
    float4 wv = *(const float4*)&Wt[k * 132 + c4];
    float rv[4];
#pragma unroll
    for (int rr = 0; rr < 4; ++rr) rv[rr] = rows[(4 * g + rr) * 132 + k];
#pragma unroll
    for (int rr = 0; rr < 4; ++rr) {
      acc[rr][0] += rv[rr] * wv.x;
      acc[rr][1] += rv[rr] * wv.y;
      acc[rr][2] += rv[rr] * wv.z;
      acc[rr][3] += rv[rr] * wv.w;
    }
  }
  // bf16 store of Wh (gather operand; 2 MB total -> L2-resident)
#pragma unroll
  for (int rr = 0; rr < 4; ++rr) {
    int r = base + 4 * g + rr;
    unsigned int p0 = f2bf(acc[rr][0]) | (f2bf(acc[rr][1]) << 16);
    unsigned int p1 = f2bf(acc[rr][2]) | (f2bf(acc[rr][3]) << 16);
    *(uint2*)&Whb[(size_t)r * 64 + (c4 >> 1)] = make_uint2(p0, p1);
  }
  // fused scores: s1 = Wh@a1, s2 = Wh@a2 (32-lane shfl tree)
  {
    float4 a1v = *(const float4*)&a[c4];
    float4 a2v = *(const float4*)&a[FDIM + c4];
#pragma unroll
    for (int rr = 0; rr < 4; ++rr) {
      float d1 = acc[rr][0] * a1v.x + acc[rr][1] * a1v.y +
                 acc[rr][2] * a1v.z + acc[rr][3] * a1v.w;
      float d2 = acc[rr][0] * a2v.x + acc[rr][1] * a2v.y +
                 acc[rr][2] * a2v.z + acc[rr][3] * a2v.w;
#pragma unroll
      for (int off = 16; off; off >>= 1) {
        d1 += __shfl_down(d1, off);
        d2 += __shfl_down(d2, off);
      }
      if ((t & 31) == 0) {
        s1[base + 4 * g + rr] = d1;
        s2[base + 4 * g + rr] = d2;
      }
    }
  }
  __syncthreads();
  float4 cs = make_float4(acc[0][0] + acc[1][0] + acc[2][0] + acc[3][0],
                          acc[0][1] + acc[1][1] + acc[2][1] + acc[3][1],
                          acc[0][2] + acc[1][2] + acc[2][2] + acc[3][2],
                          acc[0][3] + acc[1][3] + acc[2][3] + acc[3][3]);
  *(float4*)&rows[g * FDIM + c4] = cs;
  __syncthreads();
  if (t < FDIM) {
    float s = 0.f;
#pragma unroll
    for (int gg = 0; gg < 8; ++gg) s += rows[gg * FDIM + t];
    atomicAdd(&S[t], s);
  }
}

// non-temporal float4 load: adj is streamed exactly once — keep it out of
// the L2 working set so Whb (2 MB) stays resident for the gather phase.
__device__ __forceinline__ float4 ntload4(const float4* p) {
  typedef float f4v __attribute__((ext_vector_type(4)));
  f4v v = __builtin_nontemporal_load((const f4v*)p);
  return make_float4(v[0], v[1], v[2], v[3]);
}

// exact wave64 prefix-popcount of ballot mask below this lane (2 VALU ops)
__device__ __forceinline__ int mbcnt64(unsigned long long b) {
  return (int)__builtin_amdgcn_mbcnt_hi(
      (unsigned)(b >> 32), __builtin_amdgcn_mbcnt_lo((unsigned)b, 0u));
}

// ---------------- Kernel B: per-row softmax + sparse gather ----------------
// EXACT round-2 structure (the measured best, 404.1) with ONE variable
// changed: occupancy. launch_bounds(256,8) -> 8 blocks/CU (LDS 18.5 KB x 8
// = 148 KB fits; VGPR capped at 64, so the scan prefetch is split into two
// 4-chunk passes = 16 payload VGPRs). All five schedule-level restructures
// (r2-r6) were flat at 4 blocks/CU; doubling resident blocks doubles both
// outstanding HBM bytes and gather-phase MLP per CU — the first-class
// latency-hiding lever not yet tried.
__global__ __launch_bounds__(256, 8) void gat_row_kernel(
    const float* __restrict__ adj, const unsigned int* __restrict__ Whb,
    const float* __restrict__ s1, const float* __restrict__ s2,
    const float* __restrict__ S, float* __restrict__ out) {
  const int i = blockIdx.x;
  const int t = threadIdx.x;
  const int lane = t & 63;
  const int wave = t >> 6;
  __shared__ float2 pairs[4 * SEG];  // .x = e then p ; .y = j (int bits)
  __shared__ int counts[4];
  __shared__ float red[4];           // per-wave max
  __shared__ float red2[4];          // per-wave exp-sum
  __shared__ float fpart[4][FDIM];

  const float s1i = s1[i];
  const float4* __restrict__ arow = (const float4*)(adj + (size_t)i * N_NODES);
  float2* __restrict__ mypairs = pairs + wave * SEG;

  // ---- scan: two 4-chunk passes (16 payload VGPRs), ballot compaction ----
  int cbase = 0;
#pragma unroll
  for (int half8 = 0; half8 < 2; ++half8) {
    float4 av[4];
#pragma unroll
    for (int it = 0; it < 4; ++it)
      av[it] = ntload4(&arow[(half8 * 4 + it) * 256 + t]);
#pragma unroll
    for (int it = 0; it < 4; ++it) {
      const int j4 = (half8 * 4 + it) * 256 + t;
      float v[4] = {av[it].x, av[it].y, av[it].z, av[it].w};
#pragma unroll
      for (int c = 0; c < 4; ++c) {
        bool pred = (v[c] != 0.f);
        unsigned long long b = __ballot(pred);
        if (pred) {
          int pos = cbase + mbcnt64(b);
          if (pos < SEG) ((int*)&mypairs[pos])[1] = j4 * 4 + c;
        }
        cbase += (int)__popcll(b);
      }
    }
  }
  const int mycnt = cbase < SEG ? cbase : SEG;
  if (lane == 0) counts[wave] = mycnt;

  // ---- phase2: e from s2[j] gathers (L1/L2-hot), wave max ----
  float lmax = -1e30f;
  for (int k = lane; k < mycnt; k += 64) {
    int j = ((const int*)&mypairs[k])[1];
    float e = s1i + s2[j];
    e = e > 0.f ? e : NEG_SLOPE * e;
    mypairs[k].x = e;
    lmax = fmaxf(lmax, e);
  }
  for (int off = 32; off; off >>= 1) lmax = fmaxf(lmax, __shfl_down(lmax, off));
  if (lane == 0) red[wave] = lmax;
  __syncthreads();
  const int cnt = counts[0] + counts[1] + counts[2] + counts[3];
  float m = fmaxf(fmaxf(red[0], red[1]), fmaxf(red[2], red[3]));
  if (cnt < N_NODES) m = fmaxf(m, 0.f);  // adj==0 entries contribute z=0
  const float em = __expf(-m);

  // ---- phase3: p = exp(e-m) once per pair, wave sum ----
  float lsum = 0.f;
  for (int k = lane; k < mycnt; k += 64) {
    float p = __expf(mypairs[k].x - m);
    mypairs[k].x = p;
    lsum += p;
  }
  for (int off = 32; off; off >>= 1) lsum += __shfl_down(lsum, off);
  if (lane == 0) red2[wave] = lsum;
  // no barrier needed: gather below reads only this wave's own segment

  // ---- gather: half-wave per pair, bf16 rows, 4-deep unroll ----
  const int half = lane >> 5, lq = lane & 31;
  const uint2* __restrict__ Whb2 = (const uint2*)Whb;  // 32 x uint2 per row
  float ax = 0.f, ay = 0.f, az = 0.f, aw = 0.f;
  const int nit = (mycnt + 1) >> 1;
  int it = 0;
  for (; it + 3 < nit; it += 4) {
#pragma unroll
    for (int c = 0; c < 4; ++c) {
      int p = 2 * (it + c) + half;
      bool ok = p < mycnt;
      float2 pr = mypairs[ok ? p : 0];
      int j = ((const int*)&pr)[1];
      uint2 d = Whb2[((size_t)j << 5) + lq];
      float w = ok ? pr.x - em : 0.f;
      ax += w * __uint_as_float(d.x << 16);
      ay += w * __uint_as_float(d.x & 0xffff0000u);
      az += w * __uint_as_float(d.y << 16);
      aw += w * __uint_as_float(d.y & 0xffff0000u);
    }
  }
  for (; it < nit; ++it) {
    int p = 2 * it + half;
    bool ok = p < mycnt;
    float2 pr = mypairs[ok ? p : 0];
    int j = ((const int*)&pr)[1];
    uint2 d = Whb2[((size_t)j << 5) + lq];
    float w = ok ? pr.x - em : 0.f;
    ax += w * __uint_as_float(d.x << 16);
    ay += w * __uint_as_float(d.x & 0xffff0000u);
    az += w * __uint_as_float(d.y << 16);
    aw += w * __uint_as_float(d.y & 0xffff0000u);
  }
  // combine odd/even halves (same features, disjoint neighbor subsets)
  ax += __shfl_down(ax, 32);
  ay += __shfl_down(ay, 32);
  az += __shfl_down(az, 32);
  aw += __shfl_down(aw, 32);
  if (lane < 32)
    *(float4*)&fpart[wave][4 * lq] = make_float4(ax, ay, az, aw);
  __syncthreads();
  if (t < FDIM) {
    float l = red2[0] + red2[1] + red2[2] + red2[3]
              + (float)(N_NODES - cnt) * em;
    float o = (fpart[0][t] + fpart[1][t] + fpart[2][t] + fpart[3][t]
               + em * S[t]) / l;
    out[(size_t)i * FDIM + t] = o;
  }
}

extern "C" void kernel_launch(void* const* d_in, const int* in_sizes, int n_in,
                              void* d_out, int out_size, void* d_ws, size_t ws_size,
                              hipStream_t stream) {
  const float* h   = (const float*)d_in[0];
  const float* adj = (const float*)d_in[1];
  const float* W   = (const float*)d_in[2];
  const float* a   = (const float*)d_in[3];
  float* out = (float*)d_out;
  // workspace layout: Whb(bf16, N*64 uints = 2 MB) | s1[N] | s2[N] | S[F]
  unsigned int* Whb = (unsigned int*)d_ws;
  float* s1 = (float*)(Whb + (size_t)N_NODES * 64);
  float* s2 = s1 + N_NODES;
  float* S  = s2 + N_NODES;

  hipMemsetAsync(S, 0, FDIM * sizeof(float), stream);
  hipLaunchKernelGGL(wh_fused_kernel, dim3(N_NODES / 32), dim3(256), 0, stream,
                     h, W, a, Whb, s1, s2, S);
  hipLaunchKernelGGL(gat_row_kernel, dim3(N_NODES), dim3(256), 0, stream,
                     adj, Whb, s1, s2, S, out);
}